// Round 4
// baseline (1732.018 us; speedup 1.0000x reference)
//
#include <hip/hip_runtime.h>

// DIAGNOSTIC ROUND: R0's exact kernel (best scorer, 87-us envelope) plus a
// ~130 us dependent-FMA spin AFTER all stores. Purpose: push sbc_kernel into
// rocprof's top-5 so we can read its true FETCH_SIZE / WRITE_SIZE and
// discriminate RFO vs poison-drain vs hidden-second-fill theories for the
// 2x gap between kernel write BW (3.1 TB/s) and the fill's 6.5 TB/s.
// Memory behavior is bit-identical to R0; the spin touches no memory
// (asm-volatile sink keeps the chain live, guide rule #17).

#define T_PER_WAVE 2   // tiles per wave: 8192 tiles / 2 = 4096 waves
#define SPIN_ITERS 80000  // ~4cyc dependent v_fma each -> ~130 us @2.4GHz

__global__ __launch_bounds__(256) void sbc_kernel(const float* __restrict__ x,
                                                  float* __restrict__ out,
                                                  size_t mapsz) {
    const int lane = threadIdx.x & 63;               // column j
    const int wid  = blockIdx.x * 4 + (threadIdx.x >> 6);
    const int j    = lane;

    // Membership bitmask for column j: bit i set iff (i,j) is on the mask.
    const int sh = 63 - j;
    const unsigned long long mbits =
          (1ULL << j)
        | (0x7FFF000000000000ULL >> sh)
        | ((0x0000555500000000ULL >> sh) & 0x5555555555555555ULL)
        | ((0x0000000011111111ULL >> sh) & 0x1111111111111111ULL);

    const int tile0 = wid * T_PER_WAVE;

    // Preload this wave's tiles (256 B coalesced each), latencies overlapped.
    float xv[T_PER_WAVE];
#pragma unroll
    for (int tt = 0; tt < T_PER_WAVE; ++tt)
        xv[tt] = x[(size_t)(tile0 + tt) * 64 + j];

#pragma unroll
    for (int tt = 0; tt < T_PER_WAVE; ++tt) {
        const int tile = tile0 + tt;
        float* __restrict__ bout = out + (size_t)tile * 4096;
        float* __restrict__ cout = bout + mapsz;
        const float xj = xv[tt];
        float r = xj;   // finite init: masked lanes never see -inf
#pragma unroll
        for (int i = 63; i >= 0; --i) {
            const float xi = __shfl(xv[tt], i, 64);      // uniform -> v_readlane
            const float xs = (j >= i) ? xi : -INFINITY;
            r = fmaxf(r, xs);
            const bool on  = (mbits >> i) & 1ULL;
            const float s  = on ? 0.5f : 0.0f;
            const float s2 = on ? 1.0f : 0.0f;
            bout[i * 64 + j] = s * (xi + xj);
            cout[i * 64 + j] = s2 * r;
        }
        // mask: one copy per batch, owned by the tile with d==0
        if ((tile & 511) == 0) {
            float* __restrict__ mout = out + 2 * mapsz + (size_t)(tile >> 9) * 4096;
#pragma unroll
            for (int i = 0; i < 64; ++i)
                mout[i * 64 + j] = ((mbits >> i) & 1ULL) ? 1.0f : 0.0f;
        }
    }

    // ---- diagnostic spin: serial dependent FMA chain, no memory traffic ----
    float acc = xv[0];
#pragma clang loop unroll_count(4)
    for (int k = 0; k < SPIN_ITERS; ++k)
        acc = acc * 1.0000001f + 1e-30f;             // dependent v_fma chain
    asm volatile("" :: "v"(acc));                    // keep live, no store
}

extern "C" void kernel_launch(void* const* d_in, const int* in_sizes, int n_in,
                              void* d_out, int out_size, void* d_ws, size_t ws_size,
                              hipStream_t stream) {
    const float* x = (const float*)d_in[0];
    float* out = (float*)d_out;
    const int N  = 64;
    const int BD = in_sizes[0] / N;                   // 8192 tiles
    const size_t mapsz = (size_t)BD * N * N;          // 33,554,432
    const int nwaves = BD / T_PER_WAVE;               // 4096
    sbc_kernel<<<dim3(nwaves / 4), dim3(256), 0, stream>>>(x, out, mapsz);
}

// Round 5
// 546.123 us; speedup vs baseline: 3.1715x; 3.1715x over previous
//
#include <hip/hip_runtime.h>

// DIAGNOSTIC ROUND 2: R0's exact kernel with a ~150 us wall-clock spin
// BETWEEN the input loads and the stores (s_memrealtime-based, DVFS-immune).
// Purpose: discriminate the two surviving theories for the kernel's apparent
// 3.1 TB/s write phase (half the fill's 6.5 TB/s):
//   (a) conveyor/drain: the poison fill leaves ~180 MB dirty in L3; our
//       store phase stalls behind its HBM drain. Pre-draining via the spin
//       -> store phase collapses to ~41-50 us (sbc dur ~190-210).
//   (b) kernel-side write-path limit: store phase stays ~87 us regardless
//       (sbc dur ~230-245).
// Stores are data-dependent on the spin result (zoff==0 folded via inline
// asm) so they cannot be scheduled before the spin completes.

#define T_PER_WAVE 2        // tiles per wave: 8192 tiles / 2 = 4096 waves
#define DRAIN_TICKS 15000ULL  // 150 us at the 100 MHz realtime clock

__global__ __launch_bounds__(256) void sbc_kernel(const float* __restrict__ x,
                                                  float* __restrict__ out,
                                                  size_t mapsz) {
    const int lane = threadIdx.x & 63;               // column j
    const int wid  = blockIdx.x * 4 + (threadIdx.x >> 6);
    const int j    = lane;

    // Membership bitmask for column j: bit i set iff (i,j) is on the mask.
    const int sh = 63 - j;
    const unsigned long long mbits =
          (1ULL << j)
        | (0x7FFF000000000000ULL >> sh)
        | ((0x0000555500000000ULL >> sh) & 0x5555555555555555ULL)
        | ((0x0000000011111111ULL >> sh) & 0x1111111111111111ULL);

    const int tile0 = wid * T_PER_WAVE;

    // Preload this wave's tiles (256 B coalesced each).
    float xv[T_PER_WAVE];
#pragma unroll
    for (int tt = 0; tt < T_PER_WAVE; ++tt)
        xv[tt] = x[(size_t)(tile0 + tt) * 64 + j];

    // ---- pre-store drain spin: wait DRAIN_TICKS of the realtime clock ----
    const unsigned long long t0 = __builtin_amdgcn_s_memrealtime();
    unsigned guard = 0;
    while ((__builtin_amdgcn_s_memrealtime() - t0) < DRAIN_TICKS) {
        if (++guard >= (1u << 20)) break;            // hang guard
    }
    // Opaque zero derived from the spin result: forces all stores to be
    // data-dependent on spin completion (cannot be hoisted above it).
    int zoff;
    asm volatile("v_and_b32 %0, 0, %1" : "=v"(zoff) : "v"(guard));

#pragma unroll
    for (int tt = 0; tt < T_PER_WAVE; ++tt) {
        const int tile = tile0 + tt;
        float* __restrict__ bout = out + (size_t)tile * 4096 + zoff;
        float* __restrict__ cout = bout + mapsz;
        const float xj = xv[tt];
        float r = xj;   // finite init: masked lanes never see -inf
#pragma unroll
        for (int i = 63; i >= 0; --i) {
            const float xi = __shfl(xv[tt], i, 64);      // uniform -> v_readlane
            const float xs = (j >= i) ? xi : -INFINITY;
            r = fmaxf(r, xs);
            const bool on  = (mbits >> i) & 1ULL;
            const float s  = on ? 0.5f : 0.0f;
            const float s2 = on ? 1.0f : 0.0f;
            bout[i * 64 + j] = s * (xi + xj);
            cout[i * 64 + j] = s2 * r;
        }
        // mask: one copy per batch, owned by the tile with d==0
        if ((tile & 511) == 0) {
            float* __restrict__ mout = out + 2 * mapsz
                                     + (size_t)(tile >> 9) * 4096 + zoff;
#pragma unroll
            for (int i = 0; i < 64; ++i)
                mout[i * 64 + j] = ((mbits >> i) & 1ULL) ? 1.0f : 0.0f;
        }
    }
}

extern "C" void kernel_launch(void* const* d_in, const int* in_sizes, int n_in,
                              void* d_out, int out_size, void* d_ws, size_t ws_size,
                              hipStream_t stream) {
    const float* x = (const float*)d_in[0];
    float* out = (float*)d_out;
    const int N  = 64;
    const int BD = in_sizes[0] / N;                   // 8192 tiles
    const size_t mapsz = (size_t)BD * N * N;          // 33,554,432
    const int nwaves = BD / T_PER_WAVE;               // 4096
    sbc_kernel<<<dim3(nwaves / 4), dim3(256), 0, stream>>>(x, out, mapsz);
}